// Round 2
// baseline (453.629 us; speedup 1.0000x reference)
//
#include <hip/hip_runtime.h>
#include <math.h>

#define N_NODES    100000
#define K_NEIGH    32
#define OUT_STRIDE 448   // 3*128 + 64
#define SLAB       (N_NODES * 16)   // elements per 16-channel F slab

typedef __attribute__((ext_vector_type(8))) __bf16 bf16x8;
typedef __attribute__((ext_vector_type(4))) float  f32x4;

// bf16 helpers (RNE)
static __device__ __forceinline__ unsigned short f2bf(float f) {
    unsigned int u = __float_as_uint(f);
    return (unsigned short)((u + 0x7FFFu + ((u >> 16) & 1u)) >> 16);
}
static __device__ __forceinline__ float bf2f(unsigned short h) {
    return __uint_as_float(((unsigned int)h) << 16);
}

// ---------------------------------------------------------------------------
// One-shot prep: iwp[n][k] = (idx << 15) | round(exp(-10*dist)*32767).
// idx < 100000 < 2^17, weight in (0,1] -> 15-bit linear fixed point
// (abs err <= 1.5e-5, negligible vs bf16 feature error). One dword per k
// in the acc hot loop. Also bf16 transposed weights for the MFMA dense.
// ---------------------------------------------------------------------------
__global__ __launch_bounds__(256) void prep_kernel(
    const float* __restrict__ dist, const int* __restrict__ idx,
    unsigned int* __restrict__ iwp,
    const float* __restrict__ W0, const float* __restrict__ W1,
    const float* __restrict__ W2,
    unsigned short* __restrict__ Wt0, unsigned short* __restrict__ Wt1,
    unsigned short* __restrict__ Wt2)
{
    const int i = blockIdx.x * 256 + threadIdx.x;
    if (i < N_NODES * K_NEIGH) {
        const float w = __expf(-10.f * dist[i]);
        const unsigned int w15 = (unsigned int)(w * 32767.f + 0.5f);
        iwp[i] = ((unsigned int)idx[i] << 15) | w15;
    }
    if (i < 64 * 64)  Wt0[(i & 63) * 64  + (i >> 6)] = f2bf(W0[i]);  // i = k*64+n
    if (i < 128 * 64) Wt1[(i & 63) * 128 + (i >> 6)] = f2bf(W1[i]);
    if (i < 128 * 64) Wt2[(i & 63) * 128 + (i >> 6)] = f2bf(W2[i]);
}

// ---------------------------------------------------------------------------
// Dense layer via MFMA: F[n][c] = relu(b[c] + sum_k in[n][k]*W[k][c]), bf16.
// F now stored channel-BLOCKED: F[c/16][n][c%16] so each 16-channel slab is a
// contiguous 3.2 MB region (fits one XCD's 4 MB L2 for the acc gather).
// ---------------------------------------------------------------------------
template <int DIN, bool COPY_X>
__global__ __launch_bounds__(256) void dense_kernel(
    const float* __restrict__ in, int in_stride,
    const unsigned short* __restrict__ Wt,   // [64][DIN] bf16 (transposed W)
    const float* __restrict__ b,
    unsigned short* __restrict__ F, float* __restrict__ out)
{
    constexpr int LDK = DIN + 8;
    __shared__ unsigned short aLDS[64 * LDK];
    __shared__ unsigned short bLDS[64 * LDK];

    const int tid  = threadIdx.x;
    const int row0 = blockIdx.x * 64;

    // Stage A: 64 rows x DIN fp32 -> bf16 (coalesced float4 reads)
    for (int i = tid; i < 64 * (DIN / 4); i += 256) {
        const int r = i / (DIN / 4);
        const int c = (i % (DIN / 4)) * 4;
        const int n = row0 + r;
        float4 v = make_float4(0.f, 0.f, 0.f, 0.f);
        if (n < N_NODES) {
            v = *(const float4*)&in[(size_t)n * in_stride + c];
            if (COPY_X) *(float4*)&out[(size_t)n * OUT_STRIDE + 384 + c] = v;
        }
        const unsigned int u0 = (unsigned int)f2bf(v.x) | ((unsigned int)f2bf(v.y) << 16);
        const unsigned int u1 = (unsigned int)f2bf(v.z) | ((unsigned int)f2bf(v.w) << 16);
        *(uint2*)&aLDS[r * LDK + c] = make_uint2(u0, u1);
    }
    // Stage B: Wt [64][DIN] bf16 -> padded LDS (b128 copies)
    for (int i = tid; i < 64 * (DIN / 8); i += 256) {
        const int nn = i / (DIN / 8);
        const int k0 = (i % (DIN / 8)) * 8;
        *(uint4*)&bLDS[nn * LDK + k0] = *(const uint4*)&Wt[nn * DIN + k0];
    }
    __syncthreads();

    const int lane = tid & 63;
    const int wv   = tid >> 6;
    const int m    = lane & 15;
    const int quad = lane >> 4;

    f32x4 acc[4];
#pragma unroll
    for (int nb = 0; nb < 4; ++nb) acc[nb] = (f32x4){0.f, 0.f, 0.f, 0.f};

#pragma unroll
    for (int ks = 0; ks < DIN / 32; ++ks) {
        const int koff = ks * 32 + quad * 8;
        const bf16x8 afr =
            *reinterpret_cast<const bf16x8*>(&aLDS[(wv * 16 + m) * LDK + koff]);
#pragma unroll
        for (int nb = 0; nb < 4; ++nb) {
            const bf16x8 bfr =
                *reinterpret_cast<const bf16x8*>(&bLDS[(nb * 16 + m) * LDK + koff]);
            acc[nb] = __builtin_amdgcn_mfma_f32_16x16x32_bf16(afr, bfr, acc[nb], 0, 0, 0);
        }
    }

    // Epilogue: bias + relu + bf16 store into channel-blocked F
#pragma unroll
    for (int nb = 0; nb < 4; ++nb) {
        const int c    = nb * 16 + m;
        const float bc = b[c];
#pragma unroll
        for (int reg = 0; reg < 4; ++reg) {
            const int n = row0 + wv * 16 + quad * 4 + reg;
            if (n < N_NODES) {
                const float vv = fmaxf(acc[nb][reg] + bc, 0.f);
                F[(size_t)nb * SLAB + (size_t)n * 16 + m] = f2bf(vv);
            }
        }
    }
}

// ---------------------------------------------------------------------------
// KNN accumulate, v3: channel-split passes, L2-resident gathers.
//   pass = blockIdx & 3  -> with round-robin blockIdx%8 -> XCD dispatch, each
//   XCD only ever gathers from ONE 3.2 MB slab -> slab lives in that L2.
//   Per block: 64 nodes; iwp rows staged in LDS ([64][36] pad: 16B-aligned
//   b128 writes, 2-way-free bank reads). Per wave: 16 nodes (g=lane>>2),
//   4 channels/lane (cp=lane&3); gather = dwordx2, one 32 B slab row per
//   4-lane group. Full unroll 32, all gathers independent -> deep MLP.
//   Out stores nontemporal (don't evict the resident slab).
// ---------------------------------------------------------------------------
__global__ __launch_bounds__(256) void acc_kernel(
    const unsigned short* __restrict__ F,   // [4][N][16] bf16
    const unsigned int* __restrict__ iwp,   // [N][32] packed (idx<<15)|w15
    float* __restrict__ out)                // already offset to layer slab
{
    __shared__ unsigned int iwLDS[64 * 36];

    const int pass  = blockIdx.x & 3;
    const int chunk = blockIdx.x >> 2;
    const int node0 = chunk * 64;
    const int tid   = threadIdx.x;

    // Stage 64 iwp rows (2048 dwords) as 512 dwordx4
    for (int t = tid; t < 512; t += 256) {
        const int r  = t >> 3;
        const int k0 = (t & 7) * 4;
        uint4 v = make_uint4(0u, 0u, 0u, 0u);
        if (node0 + r < N_NODES)
            v = *(const uint4*)&iwp[(size_t)(node0 + r) * K_NEIGH + k0];
        *(uint4*)&iwLDS[r * 36 + k0] = v;
    }
    __syncthreads();

    const int lane = tid & 63;
    const int wv   = tid >> 6;
    const int g    = lane >> 2;      // node within wave: 0..15
    const int cp   = lane & 3;       // channel quad: 4 channels each
    const int r    = wv * 16 + g;    // node row within block
    const int n    = node0 + r;

    const unsigned short* __restrict__ Fs = F + (size_t)pass * SLAB;

    float sum[4], mx[4];
#pragma unroll
    for (int j = 0; j < 4; ++j) { sum[j] = 0.f; mx[j] = -INFINITY; }

#pragma unroll
    for (int k = 0; k < K_NEIGH; ++k) {
        const unsigned int u  = iwLDS[r * 36 + k];
        const float        wk = (float)(u & 0x7FFFu) * (1.f / 32767.f);
        const unsigned int jk = u >> 15;
        const uint2 gv = *(const uint2*)&Fs[(size_t)jk * 16 + cp * 4];
#pragma unroll
        for (int d = 0; d < 2; ++d) {
            const unsigned int uu = (&gv.x)[d];
            const float t0 = wk * __uint_as_float(uu << 16);
            const float t1 = wk * __uint_as_float(uu & 0xffff0000u);
            sum[2 * d]     += t0;
            sum[2 * d + 1] += t1;
            mx[2 * d]      = fmaxf(mx[2 * d], t0);
            mx[2 * d + 1]  = fmaxf(mx[2 * d + 1], t1);
        }
    }

    if (n < N_NODES) {
        // prev = F[n][pass*16 + cp*4 .. +4)
        const uint2 pv = *(const uint2*)&Fs[(size_t)n * 16 + cp * 4];
        float pvf[4];
#pragma unroll
        for (int d = 0; d < 2; ++d) {
            const unsigned int uu = (&pv.x)[d];
            pvf[2 * d]     = __uint_as_float(uu << 16);
            pvf[2 * d + 1] = __uint_as_float(uu & 0xffff0000u);
        }
        const float s = 1.f / 32.f;
        f32x4 vm = {sum[0] * s - pvf[0], sum[1] * s - pvf[1],
                    sum[2] * s - pvf[2], sum[3] * s - pvf[3]};
        f32x4 vx = {mx[0] - pvf[0], mx[1] - pvf[1],
                    mx[2] - pvf[2], mx[3] - pvf[3]};
        float* orow = out + (size_t)n * OUT_STRIDE + pass * 16 + cp * 4;
        __builtin_nontemporal_store(vm, (f32x4*)(orow));
        __builtin_nontemporal_store(vx, (f32x4*)(orow + 64));
    }
}

// ---------------------------------------------------------------------------
extern "C" void kernel_launch(void* const* d_in, const int* in_sizes, int n_in,
                              void* d_out, int out_size, void* d_ws, size_t ws_size,
                              hipStream_t stream)
{
    const float* x    = (const float*)d_in[0];
    const int*   idx  = (const int*)  d_in[1];
    const float* dist = (const float*)d_in[2];
    const float* W0   = (const float*)d_in[3];
    const float* b0   = (const float*)d_in[4];
    const float* W1   = (const float*)d_in[5];
    const float* b1   = (const float*)d_in[6];
    const float* W2   = (const float*)d_in[7];
    const float* b2   = (const float*)d_in[8];

    float* out = (float*)d_out;

    // Workspace layout (all 16B-aligned):
    char* ws = (char*)d_ws;
    unsigned short* F   = (unsigned short*)(ws);                 // 12.8 MB
    unsigned int*   iwp = (unsigned int*)  (ws + 12800000);      // 12.8 MB
    unsigned short* Wt0 = (unsigned short*)(ws + 25600000);      // 8 KB
    unsigned short* Wt1 = (unsigned short*)(ws + 25608192);      // 16 KB
    unsigned short* Wt2 = (unsigned short*)(ws + 25624576);      // 16 KB

    const int prep_grid  = (N_NODES * K_NEIGH + 255) / 256;  // 12500
    const int dense_grid = (N_NODES + 63) / 64;              // 1563
    const int acc_grid   = 4 * ((N_NODES + 63) / 64);        // 6252 (pass = blk&3)

    prep_kernel<<<prep_grid, 256, 0, stream>>>(dist, idx, iwp, W0, W1, W2, Wt0, Wt1, Wt2);

    // Layer 0: dense from x (also copies x into out[:,384:448])
    dense_kernel<64, true><<<dense_grid, 256, 0, stream>>>(x, 64, Wt0, b0, F, out);
    acc_kernel<<<acc_grid, 256, 0, stream>>>(F, iwp, out + 0);

    // Layer 1: dense reads layer-0 slab of out (it IS the next input)
    dense_kernel<128, false><<<dense_grid, 256, 0, stream>>>(out + 0, OUT_STRIDE, Wt1, b1, F, nullptr);
    acc_kernel<<<acc_grid, 256, 0, stream>>>(F, iwp, out + 128);

    // Layer 2
    dense_kernel<128, false><<<dense_grid, 256, 0, stream>>>(out + 128, OUT_STRIDE, Wt2, b2, F, nullptr);
    acc_kernel<<<acc_grid, 256, 0, stream>>>(F, iwp, out + 256);
}